// Round 8
// baseline (503.726 us; speedup 1.0000x reference)
//
#include <hip/hip_runtime.h>
#include <math.h>

// Problem: B=4, S=8192, H=2048, K=4, fp32. Causal depthwise conv + SiLU.
// R8: copy-shaped GRID-STRIDE kernel. One output element (f4 group) per
// thread per iteration; all 524288 threads advance in lockstep so the
// device-wide instantaneous footprint is ONE contiguous ~8MB sliding
// window (like the 6.5 TB/s fill), instead of ~2048 scattered 8KB streams
// (the suspected 0.6x row-buffer-efficiency limiter of all strip kernels).
// x-rows are re-read 4x across neighboring iterations/threads -> cached
// loads (L2/L3 merge; FETCH_SIZE counter verifies), NT stores for y.
#define CB 4
#define CS 8192
#define CH 2048
#define CH4 (CH / 4)                 // 512 f4 groups per row
#define ROWS (CB * CS)               // 32768 rows total
#define NBLOCKS 2048
#define NTHREADS (NBLOCKS * 256)     // 524288
#define ROWS_PER_IT (NTHREADS / CH4) // 1024 rows per lockstep iteration
#define NIT (ROWS / ROWS_PER_IT)     // 32 iterations

typedef float f4 __attribute__((ext_vector_type(4)));

__device__ __forceinline__ f4 silu4(f4 v) {
    f4 r;
    r.x = v.x * __builtin_amdgcn_rcpf(1.0f + __expf(-v.x));
    r.y = v.y * __builtin_amdgcn_rcpf(1.0f + __expf(-v.y));
    r.z = v.z * __builtin_amdgcn_rcpf(1.0f + __expf(-v.z));
    r.w = v.w * __builtin_amdgcn_rcpf(1.0f + __expf(-v.w));
    return r;
}

__device__ __forceinline__ f4 conv4(f4 w0, f4 w1, f4 w2, f4 w3,
                                    f4 m3, f4 m2, f4 m1, f4 c) {
    f4 o;
    o.x = w0.x * m3.x + w0.y * m2.x + w0.z * m1.x + w0.w * c.x;
    o.y = w1.x * m3.y + w1.y * m2.y + w1.z * m1.y + w1.w * c.y;
    o.z = w2.x * m3.z + w2.y * m2.z + w2.z * m1.z + w2.w * c.z;
    o.w = w3.x * m3.w + w3.y * m2.w + w3.z * m1.w + w3.w * c.w;
    return o;
}

__global__ __launch_bounds__(256) void dwconv_silu_kernel(
        const float* __restrict__ x,
        const float* __restrict__ w,
        float* __restrict__ y) {
    const int tid = blockIdx.x * 256 + threadIdx.x;
    const int h4 = tid & (CH4 - 1);   // constant per thread -> weights in regs
    const int r0 = tid >> 9;          // starting flat row (0..1023)

    const f4* __restrict__ wv = (const f4*)w + (size_t)h4 * 4;
    const f4 w0 = wv[0], w1 = wv[1], w2 = wv[2], w3 = wv[3];

    const f4* __restrict__ xp = (const f4*)x + (size_t)r0 * CH4 + h4;
    f4* __restrict__ yp = (f4*)y + (size_t)r0 * CH4 + h4;

    const f4 zero = (f4)0.f;

    #pragma unroll 4
    for (int i = 0; i < NIT; ++i) {
        const int t = (r0 + i * ROWS_PER_IT) & (CS - 1);  // pos within batch

        // Clamp halo addresses into-range (avoids OOB for b=0, t<3), then
        // select zero for the causal pad. Conditions are wave-uniform for
        // all but the 1-in-8 waves straddling a row boundary.
        const f4* p1 = xp - (t >= 1 ? 1 * CH4 : 0);
        const f4* p2 = xp - (t >= 2 ? 2 * CH4 : 0);
        const f4* p3 = xp - (t >= 3 ? 3 * CH4 : 0);

        const f4 cur = *xp;
        const f4 v1 = *p1;
        const f4 v2 = *p2;
        const f4 v3 = *p3;

        const f4 m1 = (t >= 1) ? v1 : zero;
        const f4 m2 = (t >= 2) ? v2 : zero;
        const f4 m3 = (t >= 3) ? v3 : zero;

        const f4 o = conv4(w0, w1, w2, w3, m3, m2, m1, cur);
        __builtin_nontemporal_store(silu4(o), yp);

        xp += (size_t)ROWS_PER_IT * CH4;   // advance one device-wide window
        yp += (size_t)ROWS_PER_IT * CH4;
    }
}

extern "C" void kernel_launch(void* const* d_in, const int* in_sizes, int n_in,
                              void* d_out, int out_size, void* d_ws, size_t ws_size,
                              hipStream_t stream) {
    const float* x = (const float*)d_in[0];   // (B, S, H) fp32
    const float* w = (const float*)d_in[1];   // (H, K) fp32
    float* y = (float*)d_out;                 // (B, S, H) fp32

    dwconv_silu_kernel<<<NBLOCKS, 256, 0, stream>>>(x, w, y);
}

// Round 9
// 440.362 us; speedup vs baseline: 1.1439x; 1.1439x over previous
//
#include <hip/hip_runtime.h>
#include <math.h>

// Problem: B=4, S=8192, H=2048, K=4, fp32. Causal depthwise conv + SiLU.
// R9: single-mechanism change vs R6 (best structure, ~144us): replace ALL
// non-temporal loads/stores with regular cached accesses. Theory: NT was
// the 0.6x plateau all along — NT stores stream to HBM at fine grain
// (read/write turnaround thrash at the controller; regular stores batch
// via 32MB L2 write-back), and NT loads forfeit the ~45% L3 reuse of x
// across bench iterations that R2's FETCH=147MB proved exists.
#define CB 4
#define CS 8192
#define CH 2048
#define CH4 (CH / 4)      // 512 float4 groups per row
#define TT 32             // timesteps per thread (halo 3/32 = 9.4%)
#define TSTRIPS (CS / TT) // 256

typedef float f4 __attribute__((ext_vector_type(4)));

__device__ __forceinline__ float silu_fast(float v) {
    return v * __builtin_amdgcn_rcpf(1.0f + __expf(-v));
}

__global__ __launch_bounds__(256) void dwconv_silu_kernel(
        const float* __restrict__ x,
        const float* __restrict__ w,
        float* __restrict__ y) {
    const int tid = blockIdx.x * 256 + threadIdx.x;
    const int h4 = tid & (CH4 - 1);          // consecutive lanes -> coalesced float4 in H
    const int strip = tid >> 9;              // tid / 512
    const int b = strip >> 8;                // / TSTRIPS
    const int t0 = (strip & (TSTRIPS - 1)) * TT;

    const f4* __restrict__ xb = reinterpret_cast<const f4*>(x) + (size_t)b * CS * CH4 + h4;
    f4* __restrict__ yb = reinterpret_cast<f4*>(y) + (size_t)b * CS * CH4 + h4;

    // Weight taps for channels 4*h4 .. 4*h4+3.
    const f4* __restrict__ wv = reinterpret_cast<const f4*>(w) + (size_t)h4 * 4;
    const f4 wr0 = wv[0];
    const f4 wr1 = wv[1];
    const f4 wr2 = wv[2];
    const f4 wr3 = wv[3];

    // Sliding window rows t0-3..t0-1 (zero-padded at sequence start; t0 is
    // uniform per block so the branch is wave-uniform).
    f4 xm3 = 0.f, xm2 = 0.f, xm1 = 0.f;
    if (t0 != 0) {
        const f4* hp = xb + (size_t)(t0 - 3) * CH4;
        xm3 = hp[0];
        xm2 = hp[CH4];
        xm1 = hp[2 * CH4];
    }

    const f4* __restrict__ xp = xb + (size_t)t0 * CH4;
    f4* __restrict__ yp = yb + (size_t)t0 * CH4;

    #pragma unroll 8
    for (int i = 0; i < TT; ++i) {
        const f4 cur = *xp;

        f4 o;
        o.x = wr0.x * xm3.x + wr0.y * xm2.x + wr0.z * xm1.x + wr0.w * cur.x;
        o.y = wr1.x * xm3.y + wr1.y * xm2.y + wr1.z * xm1.y + wr1.w * cur.y;
        o.z = wr2.x * xm3.z + wr2.y * xm2.z + wr2.z * xm1.z + wr2.w * cur.z;
        o.w = wr3.x * xm3.w + wr3.y * xm2.w + wr3.z * xm1.w + wr3.w * cur.w;

        o.x = silu_fast(o.x);
        o.y = silu_fast(o.y);
        o.z = silu_fast(o.z);
        o.w = silu_fast(o.w);

        *yp = o;

        xm3 = xm2;
        xm2 = xm1;
        xm1 = cur;
        xp += CH4;
        yp += CH4;
    }
}

extern "C" void kernel_launch(void* const* d_in, const int* in_sizes, int n_in,
                              void* d_out, int out_size, void* d_ws, size_t ws_size,
                              hipStream_t stream) {
    const float* x = (const float*)d_in[0];   // (B, S, H) fp32
    const float* w = (const float*)d_in[1];   // (H, K) fp32
    float* y = (float*)d_out;                 // (B, S, H) fp32

    const int total_threads = CB * TSTRIPS * CH4;    // 4 * 256 * 512 = 524288
    dwconv_silu_kernel<<<total_threads / 256, 256, 0, stream>>>(x, w, y);
}